// Round 6
// baseline (32.209 us; speedup 1.0000x reference)
//
#include <hip/hip_runtime.h>
#include <hip/hip_bf16.h>
#include <cstdint>

// VQ-VAE vector quantize: N=65536 vectors, D=64, K=512 codes.
// d_in[0]: inputs fp32 [65536,64], d_in[1]: embeddings fp32 [512,64]
// d_out: [0]=loss, [1..4194304]=latent (gathered fp32 embeddings)
//
// R6: barrier-free main kernel. B fragments are read straight from global
// (L1/L2-resident 64 KB stream) into VGPRs with 2-deep prefetch — no LDS,
// no __syncthreads, no global_load_lds. 16 waves/CU.

typedef __attribute__((ext_vector_type(8))) short bf16x8;
typedef __attribute__((ext_vector_type(4))) float f32x4;

__device__ __forceinline__ short f2bf(float f) {
    uint32_t u = __builtin_bit_cast(uint32_t, f);
    u += 0x7FFFu + ((u >> 16) & 1u);   // round-to-nearest-even
    return (short)(u >> 16);
}

// ws layout (bytes):
//  [0, 65536)     : B fragments bf16(-e), [ct(32)][ks(2)][lane(64)] x 16B
//  [65536, 67584) : ee_t[512] fp32 = 0.5*||e_k||^2, TRANSPOSED [cb(16)][ct(32)]
//  [67584, 71680) : partials[1024] fp32
#define WS_EE   65536
#define WS_PART 67584

// ---------------- Kernel 1: setup (4 blocks x 256) ----------------
__global__ __launch_bounds__(256)
void vq_setup(const float* __restrict__ emb, char* __restrict__ ws) {
    const int tid = threadIdx.x, bid = blockIdx.x;
    bf16x8* bfrag = (bf16x8*)ws;
    float* eet = (float*)(ws + WS_EE);
    #pragma unroll
    for (int k = 0; k < 4; ++k) {
        const int s = bid * 1024 + k * 256 + tid;
        const int ct = s >> 7, ks = (s >> 6) & 1, ln = s & 63;
        const int code = (ct << 4) | (ln & 15);
        const int d0 = ks * 32 + ((ln >> 4) << 3);
        const float* src = emb + code * 64 + d0;
        float4 v0 = *(const float4*)src;
        float4 v1 = *(const float4*)(src + 4);
        bf16x8 b;
        b[0] = f2bf(-v0.x); b[1] = f2bf(-v0.y); b[2] = f2bf(-v0.z); b[3] = f2bf(-v0.w);
        b[4] = f2bf(-v1.x); b[5] = f2bf(-v1.y); b[6] = f2bf(-v1.z); b[7] = f2bf(-v1.w);
        bfrag[s] = b;
    }
    if (tid < 128) {
        const int c = bid * 128 + tid;           // code id
        const float4* e4 = (const float4*)(emb + c * 64);
        float s = 0.f;
        #pragma unroll
        for (int q = 0; q < 16; ++q) {
            float4 v = e4[q];
            s = fmaf(v.x, v.x, fmaf(v.y, v.y, fmaf(v.z, v.z, fmaf(v.w, v.w, s))));
        }
        eet[(c & 15) * 32 + (c >> 4)] = 0.5f * s;   // transposed, pre-halved
    }
}

// ---------------- Kernel 2: barrier-free main (1024 blocks x 256) ----------------
// Wave owns 16 rows (1 M-tile). B streamed global->VGPR, 2-deep prefetch.
__global__ __launch_bounds__(256, 4)
void vq_main(const float* __restrict__ flat, const float* __restrict__ emb,
             char* __restrict__ ws, float* __restrict__ out) {
    const int tid = threadIdx.x, bid = blockIdx.x;
    const int lane = tid & 63, wid = tid >> 6;
    const int cb = lane & 15;
    const int rb = bid * 64 + wid * 16;   // wave's 16 rows

    // ---- A loads: 1 M-tile x 2 k-steps x 2 float4 ----
    const int row = rb + cb;
    const float* asrc = flat + (long)row * 64 + ((lane >> 4) << 3);
    float4 ar[2][2];
    ar[0][0] = *(const float4*)asrc;
    ar[0][1] = *(const float4*)(asrc + 4);
    ar[1][0] = *(const float4*)(asrc + 32);
    ar[1][1] = *(const float4*)(asrc + 36);

    // ---- preload 0.5*||e||^2 for this lane's 32 column-classes ----
    float hv[32];
    {
        const float4* ee4 = (const float4*)(ws + WS_EE + cb * 128);
        #pragma unroll
        for (int q = 0; q < 8; ++q) {
            float4 v = ee4[q];
            hv[q * 4 + 0] = v.x; hv[q * 4 + 1] = v.y;
            hv[q * 4 + 2] = v.z; hv[q * 4 + 3] = v.w;
        }
    }

    // ---- fp32 ||x||^2 partial (this lane's 16 loaded values) ----
    float xx = 0.f;
    #pragma unroll
    for (int ks = 0; ks < 2; ++ks)
        #pragma unroll
        for (int u = 0; u < 2; ++u) {
            float4 v = ar[ks][u];
            xx = fmaf(v.x, v.x, fmaf(v.y, v.y, fmaf(v.z, v.z, fmaf(v.w, v.w, xx))));
        }

    // ---- convert A to bf16 ----
    bf16x8 a[2];
    #pragma unroll
    for (int ks = 0; ks < 2; ++ks) {
        float4 v0 = ar[ks][0], v1 = ar[ks][1];
        bf16x8 f;
        f[0] = f2bf(v0.x); f[1] = f2bf(v0.y); f[2] = f2bf(v0.z); f[3] = f2bf(v0.w);
        f[4] = f2bf(v1.x); f[5] = f2bf(v1.y); f[6] = f2bf(v1.z); f[7] = f2bf(v1.w);
        a[ks] = f;
    }

    // ---- main loop: 32 col-tiles, B straight from global (L1/L2), 2-deep prefetch ----
    float pm[4];
    #pragma unroll
    for (int i = 0; i < 4; ++i) pm[i] = __builtin_bit_cast(float, 0x7F800000u);

    const bf16x8* bg = (const bf16x8*)ws;   // [ct][ks][lane]
    bf16x8 nb0 = bg[lane];
    bf16x8 nb1 = bg[64 + lane];
    #pragma unroll 8
    for (int ct = 0; ct < 32; ++ct) {
        bf16x8 b0 = nb0, b1 = nb1;
        if (ct < 31) {
            nb0 = bg[(ct + 1) * 128 + lane];
            nb1 = bg[(ct + 1) * 128 + 64 + lane];
        }
        const int colv = (ct << 4) | cb;
        const float h = hv[ct];
        f32x4 acc = {h, h, h, h};        // 0.5||e||^2 - x.e   (B = -e)
        acc = __builtin_amdgcn_mfma_f32_16x16x32_bf16(a[0], b0, acc, 0, 0, 0);
        acc = __builtin_amdgcn_mfma_f32_16x16x32_bf16(a[1], b1, acc, 0, 0, 0);
        #pragma unroll
        for (int j = 0; j < 4; ++j) {
            uint32_t dp = (__builtin_bit_cast(uint32_t, acc[j]) & 0xFFFFFE00u) | (uint32_t)colv;
            pm[j] = fminf(pm[j], __builtin_bit_cast(float, dp));
        }
    }

    // ---- butterfly min over the 16 column-class lanes ----
    #pragma unroll
    for (int m = 1; m < 16; m <<= 1) {
        #pragma unroll
        for (int i = 0; i < 4; ++i)
            pm[i] = fminf(pm[i], __shfl_xor(pm[i], m, 64));
    }

    // ---- loss partial: sum_rows( ||x||^2 + 2*unpack(pm_min) ), wave-local ----
    float t = xx;
    if (cb == 0) {
        #pragma unroll
        for (int j = 0; j < 4; ++j) {
            float v = __builtin_bit_cast(float, __builtin_bit_cast(uint32_t, pm[j]) & 0xFFFFFE00u);
            t = fmaf(2.f, v, t);
        }
    }
    #pragma unroll
    for (int m = 32; m; m >>= 1) t += __shfl_down(t, m, 64);
    if (lane == 0) ((float*)(ws + WS_PART))[bid * 4 + wid] = t;

    // ---- broadcast winning code of each of the wave's 16 rows ----
    int idxr[16];
    #pragma unroll
    for (int r = 0; r < 16; ++r) {
        float v = __shfl(pm[r & 3], (r >> 2) << 4, 64);
        idxr[r] = (int)(__builtin_bit_cast(uint32_t, v) & 0x1FFu);
    }

    // ---- epilogue: gather fp32 emb (L2-resident) + coalesced latent store ----
    float* ob = out + 1 + (long)rb * 64;
    #pragma unroll 8
    for (int it = 0; it < 16; ++it) {
        float ev = emb[idxr[it] * 64 + lane];
        ob[it * 64 + lane] = ev;
    }
}

// ---------------- Kernel 3: deterministic final reduce (1 wave) ----------------
__global__ __launch_bounds__(64)
void vq_loss(const float* __restrict__ partials, float* __restrict__ out) {
    const int tid = threadIdx.x;
    float acc = 0.f;
    #pragma unroll
    for (int i = 0; i < 64; ++i) acc += partials[tid + i * 64];
    #pragma unroll
    for (int m = 32; m; m >>= 1) acc += __shfl_down(acc, m, 64);
    // loss = 0.25*e_loss + q_loss = 1.25 * mse (forward)
    if (tid == 0) out[0] = 1.25f * acc / 4194304.0f;
}

extern "C" void kernel_launch(void* const* d_in, const int* in_sizes, int n_in,
                              void* d_out, int out_size, void* d_ws, size_t ws_size,
                              hipStream_t stream) {
    const float* flat = (const float*)d_in[0];   // [65536,64]
    const float* emb  = (const float*)d_in[1];   // [512,64]
    float* out = (float*)d_out;
    char* ws = (char*)d_ws;

    vq_setup<<<4, 256, 0, stream>>>(emb, ws);
    vq_main<<<1024, 256, 0, stream>>>(flat, emb, ws, out);
    vq_loss<<<1, 64, 0, stream>>>((const float*)(ws + WS_PART), out);
}